// Round 8
// baseline (267.182 us; speedup 1.0000x reference)
//
#include <hip/hip_runtime.h>

// Problem constants (match reference)
#define H_    64
#define W_    1024
#define NPT   65536            // H*W
#define NTOT  131072           // B*NPT
#define C1_   64
#define C2_   128
#define CIN_  192
#define CM_   128
#define NS_   3
#define DIST2_ 10000.0f
#define BN_EPS_ 1e-5f
#define NSLOT 32               // BN-stat accumulator slots
#define XP    132              // LDS row pitch (elements) for 128-wide tiles

typedef __attribute__((ext_vector_type(8))) short short8;   // 8 bf16
typedef __attribute__((ext_vector_type(4))) float floatx4;  // MFMA C/D

static __device__ __forceinline__ unsigned short f2bf(float f) {
    unsigned int u = __float_as_uint(f);
    u += 0x7fffu + ((u >> 16) & 1u);      // round-nearest-even
    return (unsigned short)(u >> 16);
}
static __device__ __forceinline__ float bflo(unsigned u) { return __uint_as_float(u << 16); }
static __device__ __forceinline__ float bfhi(unsigned u) { return __uint_as_float(u & 0xffff0000u); }
static __device__ __forceinline__ unsigned packbf(float a, float b) {
    return (unsigned)f2bf(a) | ((unsigned)f2bf(b) << 16);
}

// ---------------------------------------------------------------------------
// K0 (tiny): build fragment-major bf16 weights.
// ---------------------------------------------------------------------------
__global__ __launch_bounds__(256) void prep_w_kernel(
    const float* __restrict__ w0, const float* __restrict__ w1,
    unsigned short* __restrict__ w0F, unsigned short* __restrict__ w1F)
{
    int tid = blockIdx.x * 256 + threadIdx.x;
    if (tid < 3072) {                       // w0F: 6kk x 8nt x 64lane chunks
        int c = tid, lane = c & 63, nt = (c >> 6) & 7, kk = c >> 9;
        int n = nt * 16 + (lane & 15);
        int kb = kk * 32 + (lane >> 4) * 8;
        #pragma unroll
        for (int j = 0; j < 8; j++)
            w0F[(size_t)c * 8 + j] = f2bf(w0[(size_t)(kb + j) * CM_ + n]);
    } else if (tid < 5120) {                // w1F: 4kk x 8nt x 64lane
        int c = tid - 3072, lane = c & 63, nt = (c >> 6) & 7, kk = c >> 9;
        int n = nt * 16 + (lane & 15);
        int kb = kk * 32 + (lane >> 4) * 8;
        #pragma unroll
        for (int j = 0; j < 8; j++)
            w1F[(size_t)c * 8 + j] = f2bf(w1[(size_t)(kb + j) * CM_ + n]);
    }
}

// Redundant per-block BN finish (bit-identical in every block).
static __device__ __forceinline__ void bn_finish_lds(
    const float* __restrict__ slots, const float* __restrict__ g,
    const float* __restrict__ be, float* bnpL, int t)
{
    if (t < CM_) {
        float s = 0.f, q2 = 0.f;
        #pragma unroll
        for (int sl = 0; sl < NSLOT; sl++) {
            s  += slots[sl * 256 + t];
            q2 += slots[sl * 256 + CM_ + t];
        }
        const float invn = 1.0f / (float)NTOT;
        float mu = s * invn, var = q2 * invn - mu * mu;
        float sc = g[t] * rsqrtf(var + BN_EPS_);
        bnpL[t] = sc;
        bnpL[CM_ + t] = be[t] - mu * sc;
    }
}

// ---------------------------------------------------------------------------
// fused1 body, shared by the real kernel (MODE=0 full grid) and the
// quarter-size ablation probes:
//   MODE 0: faithful
//   MODE 1: gather pattern -> block-local contiguous rows (KNN kept live via
//           wgt; 3 distinct rows per point so no CSE) -- isolates gather
//   MODE 2: MFMA + w0F loads removed (acc fed from xstage+af, DCE-proof)
// ---------------------------------------------------------------------------
template<int MODE>
static __device__ __forceinline__ void fused1_body(
    const float* __restrict__ xyz1, const float* __restrict__ xyz2,
    const float* __restrict__ feat1, const float* __restrict__ feat2,
    const unsigned short* __restrict__ w0F, const float* __restrict__ b0,
    uint2* __restrict__ y0w, float* __restrict__ slots0)
{
    __shared__ unsigned short xstage[64][XP];
    __shared__ int   selL[64][NS_];
    __shared__ float wgtL[64][NS_];
    __shared__ float wsum[4][CM_], wsq[4][CM_];

    const int t = threadIdx.x;
    const int blk = blockIdx.x;
    const int pbase = blk * 64;
    const int bidx = blk >> 10;
    const int wv = t >> 6, lane = t & 63;
    const int m = lane & 15, q = lane >> 4;
    const int lr = wv * 16 + m;
    const int row0 = pbase + lr;

    short8 af[2];
    #pragma unroll
    for (int kk = 0; kk < 2; kk++) {
        const float* sp = feat1 + (size_t)row0 * C1_ + kk * 32 + q * 8;
        float4 fa = *(const float4*)(sp), fb = *(const float4*)(sp + 4);
        short8 a;
        a[0] = f2bf(fa.x); a[1] = f2bf(fa.y); a[2] = f2bf(fa.z); a[3] = f2bf(fa.w);
        a[4] = f2bf(fb.x); a[5] = f2bf(fb.y); a[6] = f2bf(fb.z); a[7] = f2bf(fb.w);
        af[kk] = a;
    }

    if (t < 64) {
        const int pt = pbase + t;
        const int n = pt & (NPT - 1);
        const int h = n >> 10, w = n & (W_ - 1);
        const float* p1 = xyz1 + (size_t)pt * 3;
        float x1 = p1[0], y1 = p1[1], z1 = p1[2];
        const float* x2b = xyz2 + (size_t)bidx * NPT * 3;

        float sq[25];
        #pragma unroll
        for (int k = 0; k < 25; k++) {
            const int dh = k / 5 - 2, dw = k % 5 - 2;
            int nh = h + dh, nw = w + dw;
            bool inb = (nh >= 0) && (nh < H_) && (nw >= 0) && (nw < W_);
            int ch = min(max(nh, 0), H_ - 1);
            int cw = min(max(nw, 0), W_ - 1);
            const float* p2 = x2b + (size_t)(ch * W_ + cw) * 3;
            float dx = p2[0] - x1, dy = p2[1] - y1, dz = p2[2] - z1;
            float s = dx * dx + dy * dy + dz * dz;
            sq[k] = inb ? s : 3.4e38f;
        }
        int   s0 = 0, s1 = 0, s2 = 0;
        float d0 = 0.f, d1 = 0.f, d2 = 0.f;
        int cnt = 0;
        #pragma unroll
        for (int k = 0; k < 25; k++) {
            const int dh = k / 5 - 2, dw = k % 5 - 2;
            int ch = min(max(h + dh, 0), H_ - 1);
            int cw = min(max(w + dw, 0), W_ - 1);
            int nidx = ch * W_ + cw;
            if (sq[k] < DIST2_ && cnt < NS_) {
                if (cnt == 0)      { s0 = nidx; d0 = sq[k]; }
                else if (cnt == 1) { s1 = nidx; d1 = sq[k]; }
                else               { s2 = nidx; d2 = sq[k]; }
                cnt++;
            }
        }
        float self2 = x1 * x1 + y1 * y1 + z1 * z1;
        float dd0 = (cnt > 0) ? d0 : self2;
        float dd1 = (cnt > 1) ? d1 : self2;
        float dd2 = (cnt > 2) ? d2 : self2;
        dd0 = fmaxf(dd0, 1e-10f); dd1 = fmaxf(dd1, 1e-10f); dd2 = fmaxf(dd2, 1e-10f);
        float i0 = 1.0f / dd0, i1 = 1.0f / dd1, i2 = 1.0f / dd2;
        float norm = i0 + i1 + i2;
        selL[t][0] = (cnt > 0) ? s0 : 0;
        selL[t][1] = (cnt > 1) ? s1 : 0;
        selL[t][2] = (cnt > 2) ? s2 : 0;
        wgtL[t][0] = (cnt > 0) ? i0 / norm : 0.f;
        wgtL[t][1] = (cnt > 1) ? i1 / norm : 0.f;
        wgtL[t][2] = (cnt > 2) ? i2 / norm : 0.f;
    }
    __syncthreads();

    // IDW interp -> xstage
    const float* f2b = feat2 + (size_t)bidx * NPT * C2_;
    #pragma unroll
    for (int i = 0; i < 8; i++) {
        int idx = t + i * 256;
        int p = idx >> 5, c4 = (idx & 31) << 2;
        float ax = 0.f, ay = 0.f, az = 0.f, aw = 0.f;
        #pragma unroll
        for (int j = 0; j < NS_; j++) {
            float wj = wgtL[p][j];
            int srow = (MODE == 1) ? (pbase + ((p + j * 17) & 63))  // contiguous window
                                   : selL[p][j];
            const float4 f = *(const float4*)(f2b + (size_t)srow * C2_ + c4);
            ax += wj * f.x; ay += wj * f.y; az += wj * f.z; aw += wj * f.w;
        }
        ushort4 u;
        u.x = f2bf(ax); u.y = f2bf(ay); u.z = f2bf(az); u.w = f2bf(aw);
        *(ushort4*)&xstage[p][c4] = u;
    }
    __syncthreads();

    floatx4 acc[8];
    #pragma unroll
    for (int nt = 0; nt < 8; nt++) acc[nt] = (floatx4){0.f, 0.f, 0.f, 0.f};

    if (MODE != 2) {
        #pragma unroll
        for (int kk = 0; kk < 6; kk++) {
            short8 bw[8];
            #pragma unroll
            for (int nt = 0; nt < 8; nt++)
                bw[nt] = *(const short8*)(w0F + ((size_t)(kk * 8 + nt) * 64 + lane) * 8);
            short8 a = (kk < 2) ? af[kk]
                                : *(const short8*)&xstage[lr][(kk - 2) * 32 + q * 8];
            #pragma unroll
            for (int nt = 0; nt < 8; nt++)
                acc[nt] = __builtin_amdgcn_mfma_f32_16x16x32_bf16(a, bw[nt], acc[nt], 0, 0, 0);
        }
    } else {
        // keep xstage + af live without MFMA/w0F (rule #17: no DCE of gather)
        #pragma unroll
        for (int nt = 0; nt < 8; nt++) {
            #pragma unroll
            for (int j = 0; j < 4; j++)
                acc[nt][j] = (float)xstage[lr][nt * 16 + j] + (float)(short)af[nt & 1][j];
        }
    }

    #pragma unroll
    for (int nt = 0; nt < 8; nt++) {
        int n = nt * 16 + m;
        float bv = b0[n];
        unsigned u0 = packbf(acc[nt][0] + bv, acc[nt][1] + bv);
        unsigned u1 = packbf(acc[nt][2] + bv, acc[nt][3] + bv);
        y0w[((size_t)(blk * 4 + wv) * 8 + nt) * 64 + lane] = make_uint2(u0, u1);
        float v0 = bflo(u0), v1 = bfhi(u0), v2 = bflo(u1), v3 = bfhi(u1);
        float s  = v0 + v1 + v2 + v3;
        float q2 = v0*v0 + v1*v1 + v2*v2 + v3*v3;
        s += __shfl_xor(s, 16, 64); q2 += __shfl_xor(q2, 16, 64);
        s += __shfl_xor(s, 32, 64); q2 += __shfl_xor(q2, 32, 64);
        if (q == 0) { wsum[wv][n] = s; wsq[wv][n] = q2; }
    }
    __syncthreads();

    float* slot = slots0 + (size_t)(blk & (NSLOT - 1)) * 256;
    if (t < CM_)
        atomicAdd(&slot[t], wsum[0][t] + wsum[1][t] + wsum[2][t] + wsum[3][t]);
    else
        atomicAdd(&slot[t], wsq[0][t - CM_] + wsq[1][t - CM_] + wsq[2][t - CM_] + wsq[3][t - CM_]);
}

__global__ __launch_bounds__(256, 2) void fused1_kernel(
    const float* __restrict__ xyz1, const float* __restrict__ xyz2,
    const float* __restrict__ feat1, const float* __restrict__ feat2,
    const unsigned short* __restrict__ w0F, const float* __restrict__ b0,
    uint2* __restrict__ y0w, float* __restrict__ slots0)
{
    fused1_body<0>(xyz1, xyz2, feat1, feat2, w0F, b0, y0w, slots0);
}

// quarter-size ablation probes (write only to workspace scratch)
template<int MODE>
__global__ __launch_bounds__(256, 2) void probe1_kernel(
    const float* __restrict__ xyz1, const float* __restrict__ xyz2,
    const float* __restrict__ feat1, const float* __restrict__ feat2,
    const unsigned short* __restrict__ w0F, const float* __restrict__ b0,
    uint2* __restrict__ y0w, float* __restrict__ slots0)
{
    fused1_body<MODE>(xyz1, xyz2, feat1, feat2, w0F, b0, y0w, slots0);
}

// pure-BW / clock sanity probe: 33.5 MB coalesced read
__global__ __launch_bounds__(256) void probe_stream_kernel(
    const float4* __restrict__ src, float* __restrict__ dst)
{
    int gid = blockIdx.x * 256 + threadIdx.x;
    float4 s = {0.f, 0.f, 0.f, 0.f};
    #pragma unroll
    for (int i = 0; i < 16; i++) {
        float4 v = src[(size_t)gid + (size_t)i * 131072];
        s.x += v.x; s.y += v.y; s.z += v.z; s.w += v.w;
    }
    dst[gid] = s.x + s.y + s.z + s.w;
}

// ---------------------------------------------------------------------------
// K2: unchanged from round 7.
// ---------------------------------------------------------------------------
__global__ __launch_bounds__(256, 2) void fused2_kernel(
    const uint2* __restrict__ y0w, const float* __restrict__ slots0,
    const float* __restrict__ g0, const float* __restrict__ be0,
    const unsigned short* __restrict__ w1F, const float* __restrict__ b1,
    uint2* __restrict__ y1w, float* __restrict__ slots1)
{
    __shared__ unsigned short x1s[64][XP];
    __shared__ float wsum[4][CM_], wsq[4][CM_];
    __shared__ float bnpL[2 * CM_];

    const int t = threadIdx.x;
    const int blk = blockIdx.x;
    const int wv = t >> 6, lane = t & 63;
    const int m = lane & 15, q = lane >> 4;
    const int lr = wv * 16 + m;

    bn_finish_lds(slots0, g0, be0, bnpL, t);
    __syncthreads();

    #pragma unroll
    for (int nt = 0; nt < 8; nt++) {
        int n = nt * 16 + m;
        float sc = bnpL[n], sh = bnpL[CM_ + n];
        uint2 ua = y0w[((size_t)(blk * 4 + wv) * 8 + nt) * 64 + lane];
        int rb = wv * 16 + q * 4;
        x1s[rb + 0][n] = f2bf(fmaxf(bflo(ua.x) * sc + sh, 0.f));
        x1s[rb + 1][n] = f2bf(fmaxf(bfhi(ua.x) * sc + sh, 0.f));
        x1s[rb + 2][n] = f2bf(fmaxf(bflo(ua.y) * sc + sh, 0.f));
        x1s[rb + 3][n] = f2bf(fmaxf(bfhi(ua.y) * sc + sh, 0.f));
    }
    __syncthreads();

    floatx4 acc[8];
    #pragma unroll
    for (int nt = 0; nt < 8; nt++) acc[nt] = (floatx4){0.f, 0.f, 0.f, 0.f};

    #pragma unroll
    for (int kk = 0; kk < 4; kk++) {
        short8 bw[8];
        #pragma unroll
        for (int nt = 0; nt < 8; nt++)
            bw[nt] = *(const short8*)(w1F + ((size_t)(kk * 8 + nt) * 64 + lane) * 8);
        short8 a = *(const short8*)&x1s[lr][kk * 32 + q * 8];
        #pragma unroll
        for (int nt = 0; nt < 8; nt++)
            acc[nt] = __builtin_amdgcn_mfma_f32_16x16x32_bf16(a, bw[nt], acc[nt], 0, 0, 0);
    }

    #pragma unroll
    for (int nt = 0; nt < 8; nt++) {
        int n = nt * 16 + m;
        float bv = b1[n];
        unsigned u0 = packbf(acc[nt][0] + bv, acc[nt][1] + bv);
        unsigned u1 = packbf(acc[nt][2] + bv, acc[nt][3] + bv);
        y1w[((size_t)(blk * 4 + wv) * 8 + nt) * 64 + lane] = make_uint2(u0, u1);
        float v0 = bflo(u0), v1 = bfhi(u0), v2 = bflo(u1), v3 = bfhi(u1);
        float s  = v0 + v1 + v2 + v3;
        float q2 = v0*v0 + v1*v1 + v2*v2 + v3*v3;
        s += __shfl_xor(s, 16, 64); q2 += __shfl_xor(q2, 16, 64);
        s += __shfl_xor(s, 32, 64); q2 += __shfl_xor(q2, 32, 64);
        if (q == 0) { wsum[wv][n] = s; wsq[wv][n] = q2; }
    }
    __syncthreads();

    float* slot = slots1 + (size_t)(blk & (NSLOT - 1)) * 256;
    if (t < CM_)
        atomicAdd(&slot[t], wsum[0][t] + wsum[1][t] + wsum[2][t] + wsum[3][t]);
    else
        atomicAdd(&slot[t], wsq[0][t - CM_] + wsq[1][t - CM_] + wsq[2][t - CM_] + wsq[3][t - CM_]);
}

// ---------------------------------------------------------------------------
// K3: unchanged from round 7.
// ---------------------------------------------------------------------------
__global__ __launch_bounds__(256) void bn_out_kernel(
    const uint2* __restrict__ y1w, const float* __restrict__ slots1,
    const float* __restrict__ g1, const float* __restrict__ be1,
    float* __restrict__ out)
{
    __shared__ float xo[64][XP];
    __shared__ float bnpL[2 * CM_];
    const int t = threadIdx.x;
    const int blk = blockIdx.x;
    const int wv = t >> 6, lane = t & 63;
    const int m = lane & 15, q = lane >> 4;

    bn_finish_lds(slots1, g1, be1, bnpL, t);
    __syncthreads();

    #pragma unroll
    for (int nt = 0; nt < 8; nt++) {
        int n = nt * 16 + m;
        float sc = bnpL[n], sh = bnpL[CM_ + n];
        uint2 u = y1w[((size_t)(blk * 4 + wv) * 8 + nt) * 64 + lane];
        int rb = wv * 16 + q * 4;
        xo[rb + 0][n] = fmaxf(bflo(u.x) * sc + sh, 0.f);
        xo[rb + 1][n] = fmaxf(bfhi(u.x) * sc + sh, 0.f);
        xo[rb + 2][n] = fmaxf(bflo(u.y) * sc + sh, 0.f);
        xo[rb + 3][n] = fmaxf(bfhi(u.y) * sc + sh, 0.f);
    }
    __syncthreads();

    const int pbase = blk * 64;
    #pragma unroll
    for (int i = 0; i < 8; i++) {
        int idx = t + i * 256;
        int p = idx >> 5, c4 = (idx & 31) << 2;
        float4 v = *(const float4*)&xo[p][c4];
        *(float4*)(out + (size_t)(pbase + p) * CM_ + c4) = v;
    }
}

// ---------------------------------------------------------------------------
extern "C" void kernel_launch(void* const* d_in, const int* in_sizes, int n_in,
                              void* d_out, int out_size, void* d_ws, size_t ws_size,
                              hipStream_t stream)
{
    const float* xyz1  = (const float*)d_in[0];
    const float* xyz2  = (const float*)d_in[1];
    const float* feat1 = (const float*)d_in[2];
    const float* feat2 = (const float*)d_in[3];
    const float* w0    = (const float*)d_in[4];
    const float* b0    = (const float*)d_in[5];
    const float* g0    = (const float*)d_in[6];
    const float* be0   = (const float*)d_in[7];
    const float* w1    = (const float*)d_in[8];
    const float* b1    = (const float*)d_in[9];
    const float* g1    = (const float*)d_in[10];
    const float* be1   = (const float*)d_in[11];
    float* out = (float*)d_out;

    char* ws = (char*)d_ws;
    // ws: slots0 32K | slots1 32K | w0F 48K | w1F 32K | y0w 33.5M | y1w 33.5M
    //   | probe scratch (y0 8M, slots 32K, stream 512K)
    float* slots0       = (float*)(ws);
    float* slots1       = (float*)(ws + (size_t)NSLOT * 256 * 4);
    char*  p            = ws + 2 * (size_t)NSLOT * 256 * 4;
    unsigned short* w0F = (unsigned short*)p;  p += (size_t)CIN_ * CM_ * 2;
    unsigned short* w1F = (unsigned short*)p;  p += (size_t)CM_ * CM_ * 2;
    uint2* y0w          = (uint2*)p;           p += (size_t)NTOT * CM_ * 2;
    uint2* y1w          = (uint2*)p;           p += (size_t)NTOT * CM_ * 2;
    uint2* y0scr        = (uint2*)p;           p += (size_t)8 * 1024 * 1024;
    float* pslots       = (float*)p;           p += (size_t)NSLOT * 256 * 4;
    float* sout         = (float*)p;

    hipMemsetAsync(ws, 0, 2 * (size_t)NSLOT * 256 * 4, stream);  // zero stat slots

    prep_w_kernel<<<20, 256, 0, stream>>>(w0, w1, w0F, w1F);
    fused1_kernel<<<NTOT / 64, 256, 0, stream>>>(xyz1, xyz2, feat1, feat2,
                                                 w0F, b0, y0w, slots0);
    fused2_kernel<<<NTOT / 64, 256, 0, stream>>>(y0w, slots0, g0, be0,
                                                 w1F, b1, y1w, slots1);
    bn_out_kernel<<<NTOT / 64, 256, 0, stream>>>(y1w, slots1, g1, be1, out);

    // --- quarter-size diagnostic probes (scratch-only; after out is written)
    probe1_kernel<0><<<512, 256, 0, stream>>>(xyz1, xyz2, feat1, feat2,
                                              w0F, b0, y0scr, pslots);
    probe1_kernel<1><<<512, 256, 0, stream>>>(xyz1, xyz2, feat1, feat2,
                                              w0F, b0, y0scr, pslots);
    probe1_kernel<2><<<512, 256, 0, stream>>>(xyz1, xyz2, feat1, feat2,
                                              w0F, b0, y0scr, pslots);
    probe_stream_kernel<<<512, 256, 0, stream>>>((const float4*)feat2, sout);
}

// Round 11
// 235.702 us; speedup vs baseline: 1.1336x; 1.1336x over previous
//
#include <hip/hip_runtime.h>

// Problem constants (match reference)
#define H_    64
#define W_    1024
#define NPT   65536            // H*W
#define NTOT  131072           // B*NPT
#define C1_   64
#define C2_   128
#define CIN_  192
#define CM_   128
#define NS_   3
#define DIST2_ 10000.0f
#define BN_EPS_ 1e-5f
#define NSLOT 32               // BN-stat accumulator slots
#define XP    132              // LDS row pitch (elements) for 128-wide tiles

typedef __attribute__((ext_vector_type(8))) short short8;   // 8 bf16
typedef __attribute__((ext_vector_type(4))) float floatx4;  // MFMA C/D

static __device__ __forceinline__ unsigned short f2bf(float f) {
    unsigned int u = __float_as_uint(f);
    u += 0x7fffu + ((u >> 16) & 1u);      // round-nearest-even
    return (unsigned short)(u >> 16);
}
static __device__ __forceinline__ float bflo(unsigned u) { return __uint_as_float(u << 16); }
static __device__ __forceinline__ float bfhi(unsigned u) { return __uint_as_float(u & 0xffff0000u); }
static __device__ __forceinline__ unsigned packbf(float a, float b) {
    return (unsigned)f2bf(a) | ((unsigned)f2bf(b) << 16);
}

// ---------------------------------------------------------------------------
// K0 (tiny): build fragment-major bf16 weights.
// ---------------------------------------------------------------------------
__global__ __launch_bounds__(256) void prep_w_kernel(
    const float* __restrict__ w0, const float* __restrict__ w1,
    unsigned short* __restrict__ w0F, unsigned short* __restrict__ w1F)
{
    int tid = blockIdx.x * 256 + threadIdx.x;
    if (tid < 3072) {                       // w0F: 6kk x 8nt x 64lane chunks
        int c = tid, lane = c & 63, nt = (c >> 6) & 7, kk = c >> 9;
        int n = nt * 16 + (lane & 15);
        int kb = kk * 32 + (lane >> 4) * 8;
        #pragma unroll
        for (int j = 0; j < 8; j++)
            w0F[(size_t)c * 8 + j] = f2bf(w0[(size_t)(kb + j) * CM_ + n]);
    } else if (tid < 5120) {                // w1F: 4kk x 8nt x 64lane
        int c = tid - 3072, lane = c & 63, nt = (c >> 6) & 7, kk = c >> 9;
        int n = nt * 16 + (lane & 15);
        int kb = kk * 32 + (lane >> 4) * 8;
        #pragma unroll
        for (int j = 0; j < 8; j++)
            w1F[(size_t)c * 8 + j] = f2bf(w1[(size_t)(kb + j) * CM_ + n]);
    }
}

// Redundant per-block BN finish (bit-identical in every block).
static __device__ __forceinline__ void bn_finish_lds(
    const float* __restrict__ slots, const float* __restrict__ g,
    const float* __restrict__ be, float* bnpL, int t)
{
    if (t < CM_) {
        float s = 0.f, q2 = 0.f;
        #pragma unroll
        for (int sl = 0; sl < NSLOT; sl++) {
            s  += slots[sl * 256 + t];
            q2 += slots[sl * 256 + CM_ + t];
        }
        const float invn = 1.0f / (float)NTOT;
        float mu = s * invn, var = q2 * invn - mu * mu;
        float sc = g[t] * rsqrtf(var + BN_EPS_);
        bnpL[t] = sc;
        bnpL[CM_ + t] = be[t] - mu * sc;
    }
}

// ---------------------------------------------------------------------------
// K1: 64 points/block, 2048 blocks. Two-pass KNN (r7). y0 stored as uint4
// (16 B/lane, nt-pairs packed): y0w4[((blk*4+wv)*4+nt2)*64+lane] holds
// channels {2*nt2, 2*nt2+1}*16+m for rows wv*16+q*4+0..3.
// ---------------------------------------------------------------------------
__global__ __launch_bounds__(256, 2) void fused1_kernel(
    const float* __restrict__ xyz1, const float* __restrict__ xyz2,
    const float* __restrict__ feat1, const float* __restrict__ feat2,
    const unsigned short* __restrict__ w0F, const float* __restrict__ b0,
    uint4* __restrict__ y0w4, float* __restrict__ slots0)
{
    __shared__ unsigned short xstage[64][XP];
    __shared__ int   selL[64][NS_];
    __shared__ float wgtL[64][NS_];
    __shared__ float wsum[4][CM_], wsq[4][CM_];

    const int t = threadIdx.x;
    const int blk = blockIdx.x;
    const int pbase = blk * 64;
    const int bidx = blk >> 10;
    const int wv = t >> 6, lane = t & 63;
    const int m = lane & 15, q = lane >> 4;
    const int lr = wv * 16 + m;
    const int row0 = pbase + lr;

    short8 af[2];
    #pragma unroll
    for (int kk = 0; kk < 2; kk++) {
        const float* sp = feat1 + (size_t)row0 * C1_ + kk * 32 + q * 8;
        float4 fa = *(const float4*)(sp), fb = *(const float4*)(sp + 4);
        short8 a;
        a[0] = f2bf(fa.x); a[1] = f2bf(fa.y); a[2] = f2bf(fa.z); a[3] = f2bf(fa.w);
        a[4] = f2bf(fb.x); a[5] = f2bf(fb.y); a[6] = f2bf(fb.z); a[7] = f2bf(fb.w);
        af[kk] = a;
    }

    if (t < 64) {
        const int pt = pbase + t;
        const int n = pt & (NPT - 1);
        const int h = n >> 10, w = n & (W_ - 1);
        const float* p1 = xyz1 + (size_t)pt * 3;
        float x1 = p1[0], y1 = p1[1], z1 = p1[2];
        const float* x2b = xyz2 + (size_t)bidx * NPT * 3;

        float sq[25];
        #pragma unroll
        for (int k = 0; k < 25; k++) {
            const int dh = k / 5 - 2, dw = k % 5 - 2;
            int nh = h + dh, nw = w + dw;
            bool inb = (nh >= 0) && (nh < H_) && (nw >= 0) && (nw < W_);
            int ch = min(max(nh, 0), H_ - 1);
            int cw = min(max(nw, 0), W_ - 1);
            const float* p2 = x2b + (size_t)(ch * W_ + cw) * 3;
            float dx = p2[0] - x1, dy = p2[1] - y1, dz = p2[2] - z1;
            float s = dx * dx + dy * dy + dz * dz;
            sq[k] = inb ? s : 3.4e38f;
        }
        int   s0 = 0, s1 = 0, s2 = 0;
        float d0 = 0.f, d1 = 0.f, d2 = 0.f;
        int cnt = 0;
        #pragma unroll
        for (int k = 0; k < 25; k++) {
            const int dh = k / 5 - 2, dw = k % 5 - 2;
            int ch = min(max(h + dh, 0), H_ - 1);
            int cw = min(max(w + dw, 0), W_ - 1);
            int nidx = ch * W_ + cw;
            if (sq[k] < DIST2_ && cnt < NS_) {
                if (cnt == 0)      { s0 = nidx; d0 = sq[k]; }
                else if (cnt == 1) { s1 = nidx; d1 = sq[k]; }
                else               { s2 = nidx; d2 = sq[k]; }
                cnt++;
            }
        }
        float self2 = x1 * x1 + y1 * y1 + z1 * z1;
        float dd0 = (cnt > 0) ? d0 : self2;
        float dd1 = (cnt > 1) ? d1 : self2;
        float dd2 = (cnt > 2) ? d2 : self2;
        dd0 = fmaxf(dd0, 1e-10f); dd1 = fmaxf(dd1, 1e-10f); dd2 = fmaxf(dd2, 1e-10f);
        float i0 = 1.0f / dd0, i1 = 1.0f / dd1, i2 = 1.0f / dd2;
        float norm = i0 + i1 + i2;
        selL[t][0] = (cnt > 0) ? s0 : 0;
        selL[t][1] = (cnt > 1) ? s1 : 0;
        selL[t][2] = (cnt > 2) ? s2 : 0;
        wgtL[t][0] = (cnt > 0) ? i0 / norm : 0.f;
        wgtL[t][1] = (cnt > 1) ? i1 / norm : 0.f;
        wgtL[t][2] = (cnt > 2) ? i2 / norm : 0.f;
    }
    __syncthreads();

    // IDW interp -> xstage
    const float* f2b = feat2 + (size_t)bidx * NPT * C2_;
    #pragma unroll
    for (int i = 0; i < 8; i++) {
        int idx = t + i * 256;
        int p = idx >> 5, c4 = (idx & 31) << 2;
        float ax = 0.f, ay = 0.f, az = 0.f, aw = 0.f;
        #pragma unroll
        for (int j = 0; j < NS_; j++) {
            float wj = wgtL[p][j];
            const float4 f = *(const float4*)(f2b + (size_t)selL[p][j] * C2_ + c4);
            ax += wj * f.x; ay += wj * f.y; az += wj * f.z; aw += wj * f.w;
        }
        ushort4 u;
        u.x = f2bf(ax); u.y = f2bf(ay); u.z = f2bf(az); u.w = f2bf(aw);
        *(ushort4*)&xstage[p][c4] = u;
    }
    __syncthreads();

    floatx4 acc[8];
    #pragma unroll
    for (int nt = 0; nt < 8; nt++) acc[nt] = (floatx4){0.f, 0.f, 0.f, 0.f};

    #pragma unroll
    for (int kk = 0; kk < 6; kk++) {
        short8 bw[8];
        #pragma unroll
        for (int nt = 0; nt < 8; nt++)
            bw[nt] = *(const short8*)(w0F + ((size_t)(kk * 8 + nt) * 64 + lane) * 8);
        short8 a = (kk < 2) ? af[kk]
                            : *(const short8*)&xstage[lr][(kk - 2) * 32 + q * 8];
        #pragma unroll
        for (int nt = 0; nt < 8; nt++)
            acc[nt] = __builtin_amdgcn_mfma_f32_16x16x32_bf16(a, bw[nt], acc[nt], 0, 0, 0);
    }

    // epilogue: y0 uint4 frag-pair stores + BN0 stats
    #pragma unroll
    for (int nt2 = 0; nt2 < 4; nt2++) {
        const int ntA = 2 * nt2, ntB = ntA + 1;
        const int nA = ntA * 16 + m, nB = ntB * 16 + m;
        float bvA = b0[nA], bvB = b0[nB];
        unsigned u0 = packbf(acc[ntA][0] + bvA, acc[ntA][1] + bvA);
        unsigned u1 = packbf(acc[ntA][2] + bvA, acc[ntA][3] + bvA);
        unsigned u2 = packbf(acc[ntB][0] + bvB, acc[ntB][1] + bvB);
        unsigned u3 = packbf(acc[ntB][2] + bvB, acc[ntB][3] + bvB);
        y0w4[((size_t)(blk * 4 + wv) * 4 + nt2) * 64 + lane] = make_uint4(u0, u1, u2, u3);
        float a0 = bflo(u0), a1 = bfhi(u0), a2 = bflo(u1), a3 = bfhi(u1);
        float b0v = bflo(u2), b1v = bfhi(u2), b2v = bflo(u3), b3v = bfhi(u3);
        float sA = a0 + a1 + a2 + a3, qA = a0*a0 + a1*a1 + a2*a2 + a3*a3;
        float sB = b0v + b1v + b2v + b3v, qB = b0v*b0v + b1v*b1v + b2v*b2v + b3v*b3v;
        sA += __shfl_xor(sA, 16, 64); qA += __shfl_xor(qA, 16, 64);
        sA += __shfl_xor(sA, 32, 64); qA += __shfl_xor(qA, 32, 64);
        sB += __shfl_xor(sB, 16, 64); qB += __shfl_xor(qB, 16, 64);
        sB += __shfl_xor(sB, 32, 64); qB += __shfl_xor(qB, 32, 64);
        if (q == 0) {
            wsum[wv][nA] = sA; wsq[wv][nA] = qA;
            wsum[wv][nB] = sB; wsq[wv][nB] = qB;
        }
    }
    __syncthreads();

    float* slot = slots0 + (size_t)(blk & (NSLOT - 1)) * 256;
    if (t < CM_)
        atomicAdd(&slot[t], wsum[0][t] + wsum[1][t] + wsum[2][t] + wsum[3][t]);
    else
        atomicAdd(&slot[t], wsq[0][t - CM_] + wsq[1][t - CM_] + wsq[2][t - CM_] + wsq[3][t - CM_]);
}

// ---------------------------------------------------------------------------
// K2: uint4 in (y0), uint4 out (y1); BN0 finished in-block.
// ---------------------------------------------------------------------------
__global__ __launch_bounds__(256, 2) void fused2_kernel(
    const uint4* __restrict__ y0w4, const float* __restrict__ slots0,
    const float* __restrict__ g0, const float* __restrict__ be0,
    const unsigned short* __restrict__ w1F, const float* __restrict__ b1,
    uint4* __restrict__ y1w4, float* __restrict__ slots1)
{
    __shared__ unsigned short x1s[64][XP];
    __shared__ float wsum[4][CM_], wsq[4][CM_];
    __shared__ float bnpL[2 * CM_];

    const int t = threadIdx.x;
    const int blk = blockIdx.x;
    const int wv = t >> 6, lane = t & 63;
    const int m = lane & 15, q = lane >> 4;
    const int lr = wv * 16 + m;

    bn_finish_lds(slots0, g0, be0, bnpL, t);
    __syncthreads();

    #pragma unroll
    for (int nt2 = 0; nt2 < 4; nt2++) {
        const int nA = (2 * nt2) * 16 + m, nB = nA + 16;
        float scA = bnpL[nA], shA = bnpL[CM_ + nA];
        float scB = bnpL[nB], shB = bnpL[CM_ + nB];
        uint4 u = y0w4[((size_t)(blk * 4 + wv) * 4 + nt2) * 64 + lane];
        int rb = wv * 16 + q * 4;
        x1s[rb + 0][nA] = f2bf(fmaxf(bflo(u.x) * scA + shA, 0.f));
        x1s[rb + 1][nA] = f2bf(fmaxf(bfhi(u.x) * scA + shA, 0.f));
        x1s[rb + 2][nA] = f2bf(fmaxf(bflo(u.y) * scA + shA, 0.f));
        x1s[rb + 3][nA] = f2bf(fmaxf(bfhi(u.y) * scA + shA, 0.f));
        x1s[rb + 0][nB] = f2bf(fmaxf(bflo(u.z) * scB + shB, 0.f));
        x1s[rb + 1][nB] = f2bf(fmaxf(bfhi(u.z) * scB + shB, 0.f));
        x1s[rb + 2][nB] = f2bf(fmaxf(bflo(u.w) * scB + shB, 0.f));
        x1s[rb + 3][nB] = f2bf(fmaxf(bfhi(u.w) * scB + shB, 0.f));
    }
    __syncthreads();

    floatx4 acc[8];
    #pragma unroll
    for (int nt = 0; nt < 8; nt++) acc[nt] = (floatx4){0.f, 0.f, 0.f, 0.f};

    #pragma unroll
    for (int kk = 0; kk < 4; kk++) {
        short8 bw[8];
        #pragma unroll
        for (int nt = 0; nt < 8; nt++)
            bw[nt] = *(const short8*)(w1F + ((size_t)(kk * 8 + nt) * 64 + lane) * 8);
        short8 a = *(const short8*)&x1s[lr][kk * 32 + q * 8];
        #pragma unroll
        for (int nt = 0; nt < 8; nt++)
            acc[nt] = __builtin_amdgcn_mfma_f32_16x16x32_bf16(a, bw[nt], acc[nt], 0, 0, 0);
    }

    #pragma unroll
    for (int nt2 = 0; nt2 < 4; nt2++) {
        const int ntA = 2 * nt2, ntB = ntA + 1;
        const int nA = ntA * 16 + m, nB = ntB * 16 + m;
        float bvA = b1[nA], bvB = b1[nB];
        unsigned u0 = packbf(acc[ntA][0] + bvA, acc[ntA][1] + bvA);
        unsigned u1 = packbf(acc[ntA][2] + bvA, acc[ntA][3] + bvA);
        unsigned u2 = packbf(acc[ntB][0] + bvB, acc[ntB][1] + bvB);
        unsigned u3 = packbf(acc[ntB][2] + bvB, acc[ntB][3] + bvB);
        y1w4[((size_t)(blk * 4 + wv) * 4 + nt2) * 64 + lane] = make_uint4(u0, u1, u2, u3);
        float a0 = bflo(u0), a1 = bfhi(u0), a2 = bflo(u1), a3 = bfhi(u1);
        float c0 = bflo(u2), c1 = bfhi(u2), c2 = bflo(u3), c3 = bfhi(u3);
        float sA = a0 + a1 + a2 + a3, qA = a0*a0 + a1*a1 + a2*a2 + a3*a3;
        float sB = c0 + c1 + c2 + c3, qB = c0*c0 + c1*c1 + c2*c2 + c3*c3;
        sA += __shfl_xor(sA, 16, 64); qA += __shfl_xor(qA, 16, 64);
        sA += __shfl_xor(sA, 32, 64); qA += __shfl_xor(qA, 32, 64);
        sB += __shfl_xor(sB, 16, 64); qB += __shfl_xor(qB, 16, 64);
        sB += __shfl_xor(sB, 32, 64); qB += __shfl_xor(qB, 32, 64);
        if (q == 0) {
            wsum[wv][nA] = sA; wsq[wv][nA] = qA;
            wsum[wv][nB] = sB; wsq[wv][nB] = qB;
        }
    }
    __syncthreads();

    float* slot = slots1 + (size_t)(blk & (NSLOT - 1)) * 256;
    if (t < CM_)
        atomicAdd(&slot[t], wsum[0][t] + wsum[1][t] + wsum[2][t] + wsum[3][t]);
    else
        atomicAdd(&slot[t], wsq[0][t - CM_] + wsq[1][t - CM_] + wsq[2][t - CM_] + wsq[3][t - CM_]);
}

// ---------------------------------------------------------------------------
// K3: uint4 in (y1); BN1 finished in-block; LDS transpose -> f32 out.
// ---------------------------------------------------------------------------
__global__ __launch_bounds__(256) void bn_out_kernel(
    const uint4* __restrict__ y1w4, const float* __restrict__ slots1,
    const float* __restrict__ g1, const float* __restrict__ be1,
    float* __restrict__ out)
{
    __shared__ float xo[64][XP];
    __shared__ float bnpL[2 * CM_];
    const int t = threadIdx.x;
    const int blk = blockIdx.x;
    const int wv = t >> 6, lane = t & 63;
    const int m = lane & 15, q = lane >> 4;

    bn_finish_lds(slots1, g1, be1, bnpL, t);
    __syncthreads();

    #pragma unroll
    for (int nt2 = 0; nt2 < 4; nt2++) {
        const int nA = (2 * nt2) * 16 + m, nB = nA + 16;
        float scA = bnpL[nA], shA = bnpL[CM_ + nA];
        float scB = bnpL[nB], shB = bnpL[CM_ + nB];
        uint4 u = y1w4[((size_t)(blk * 4 + wv) * 4 + nt2) * 64 + lane];
        int rb = wv * 16 + q * 4;
        xo[rb + 0][nA] = fmaxf(bflo(u.x) * scA + shA, 0.f);
        xo[rb + 1][nA] = fmaxf(bfhi(u.x) * scA + shA, 0.f);
        xo[rb + 2][nA] = fmaxf(bflo(u.y) * scA + shA, 0.f);
        xo[rb + 3][nA] = fmaxf(bfhi(u.y) * scA + shA, 0.f);
        xo[rb + 0][nB] = fmaxf(bflo(u.z) * scB + shB, 0.f);
        xo[rb + 1][nB] = fmaxf(bfhi(u.z) * scB + shB, 0.f);
        xo[rb + 2][nB] = fmaxf(bflo(u.w) * scB + shB, 0.f);
        xo[rb + 3][nB] = fmaxf(bfhi(u.w) * scB + shB, 0.f);
    }
    __syncthreads();

    const int pbase = blk * 64;
    #pragma unroll
    for (int i = 0; i < 8; i++) {
        int idx = t + i * 256;
        int p = idx >> 5, c4 = (idx & 31) << 2;
        float4 v = *(const float4*)&xo[p][c4];
        *(float4*)(out + (size_t)(pbase + p) * CM_ + c4) = v;
    }
}

// ---------------------------------------------------------------------------
// Diagnostic: 109 MB ideal float4 copy (binary readout via top-5 presence:
// healthy BW ~20 us -> hidden; systemic ~1.5 TB/s cap -> ~75 us -> visible).
// ---------------------------------------------------------------------------
__global__ __launch_bounds__(256) void probe_copy_kernel(
    const float4* __restrict__ a, const float4* __restrict__ b,
    float4* __restrict__ dst)
{
    size_t gid = (size_t)blockIdx.x * 256 + threadIdx.x;   // 524288 threads
    float4 s = {0.f, 0.f, 0.f, 0.f};
    #pragma unroll
    for (int i = 0; i < 8; i++) {          // 67 MB read (feat2)
        float4 v = a[gid + (size_t)i * 524288];
        s.x += v.x; s.y += v.y; s.z += v.z; s.w += v.w;
    }
    #pragma unroll
    for (int i = 0; i < 4; i++) {          // 33.5 MB read (y0 scratchpad)
        float4 v = b[gid + (size_t)i * 524288];
        s.x += v.x; s.y += v.y; s.z += v.z; s.w += v.w;
    }
    dst[gid] = s;                          // 8.4 MB write
}

// ---------------------------------------------------------------------------
extern "C" void kernel_launch(void* const* d_in, const int* in_sizes, int n_in,
                              void* d_out, int out_size, void* d_ws, size_t ws_size,
                              hipStream_t stream)
{
    const float* xyz1  = (const float*)d_in[0];
    const float* xyz2  = (const float*)d_in[1];
    const float* feat1 = (const float*)d_in[2];
    const float* feat2 = (const float*)d_in[3];
    const float* w0    = (const float*)d_in[4];
    const float* b0    = (const float*)d_in[5];
    const float* g0    = (const float*)d_in[6];
    const float* be0   = (const float*)d_in[7];
    const float* w1    = (const float*)d_in[8];
    const float* b1    = (const float*)d_in[9];
    const float* g1    = (const float*)d_in[10];
    const float* be1   = (const float*)d_in[11];
    float* out = (float*)d_out;

    char* ws = (char*)d_ws;
    // ws: slots0 32K | slots1 32K | w0F 48K | w1F 32K | y0w 33.5M | y1w 33.5M
    //   | copy scratch 8M
    float* slots0       = (float*)(ws);
    float* slots1       = (float*)(ws + (size_t)NSLOT * 256 * 4);
    char*  p            = ws + 2 * (size_t)NSLOT * 256 * 4;
    unsigned short* w0F = (unsigned short*)p;  p += (size_t)CIN_ * CM_ * 2;
    unsigned short* w1F = (unsigned short*)p;  p += (size_t)CM_ * CM_ * 2;
    uint4* y0w4         = (uint4*)p;           p += (size_t)NTOT * CM_ * 2;
    uint4* y1w4         = (uint4*)p;           p += (size_t)NTOT * CM_ * 2;
    float4* cscr        = (float4*)p;

    hipMemsetAsync(ws, 0, 2 * (size_t)NSLOT * 256 * 4, stream);  // zero stat slots

    prep_w_kernel<<<20, 256, 0, stream>>>(w0, w1, w0F, w1F);
    fused1_kernel<<<NTOT / 64, 256, 0, stream>>>(xyz1, xyz2, feat1, feat2,
                                                 w0F, b0, y0w4, slots0);
    fused2_kernel<<<NTOT / 64, 256, 0, stream>>>(y0w4, slots0, g0, be0,
                                                 w1F, b1, y1w4, slots1);
    bn_out_kernel<<<NTOT / 64, 256, 0, stream>>>(y1w4, slots1, g1, be1, out);

    // diagnostic ideal-copy probe (scratch-only, after out is written)
    probe_copy_kernel<<<2048, 256, 0, stream>>>((const float4*)feat2,
                                                (const float4*)y0w4, cscr);
}

// Round 14
// 224.912 us; speedup vs baseline: 1.1879x; 1.0480x over previous
//
#include <hip/hip_runtime.h>

// Problem constants (match reference)
#define H_    64
#define W_    1024
#define NPT   65536            // H*W
#define NTOT  131072           // B*NPT
#define C1_   64
#define C2_   128
#define CIN_  192
#define CM_   128
#define NS_   3
#define DIST2_ 10000.0f
#define BN_EPS_ 1e-5f
#define NSLOT 32               // BN-stat accumulator slots
#define XP    132              // LDS row pitch (elements) for 128-wide tiles

typedef __attribute__((ext_vector_type(8))) short short8;   // 8 bf16
typedef __attribute__((ext_vector_type(4))) float floatx4;  // MFMA C/D

static __device__ __forceinline__ unsigned short f2bf(float f) {
    unsigned int u = __float_as_uint(f);
    u += 0x7fffu + ((u >> 16) & 1u);      // round-nearest-even
    return (unsigned short)(u >> 16);
}
static __device__ __forceinline__ float bflo(unsigned u) { return __uint_as_float(u << 16); }
static __device__ __forceinline__ float bfhi(unsigned u) { return __uint_as_float(u & 0xffff0000u); }
static __device__ __forceinline__ unsigned packbf(float a, float b) {
    return (unsigned)f2bf(a) | ((unsigned)f2bf(b) << 16);
}

// ---------------------------------------------------------------------------
// K0 (tiny): build fragment-major bf16 weights.
// ---------------------------------------------------------------------------
__global__ __launch_bounds__(256) void prep_w_kernel(
    const float* __restrict__ w0, const float* __restrict__ w1,
    unsigned short* __restrict__ w0F, unsigned short* __restrict__ w1F)
{
    int tid = blockIdx.x * 256 + threadIdx.x;
    if (tid < 3072) {                       // w0F: 6kk x 8nt x 64lane chunks
        int c = tid, lane = c & 63, nt = (c >> 6) & 7, kk = c >> 9;
        int n = nt * 16 + (lane & 15);
        int kb = kk * 32 + (lane >> 4) * 8;
        #pragma unroll
        for (int j = 0; j < 8; j++)
            w0F[(size_t)c * 8 + j] = f2bf(w0[(size_t)(kb + j) * CM_ + n]);
    } else if (tid < 5120) {                // w1F: 4kk x 8nt x 64lane
        int c = tid - 3072, lane = c & 63, nt = (c >> 6) & 7, kk = c >> 9;
        int n = nt * 16 + (lane & 15);
        int kb = kk * 32 + (lane >> 4) * 8;
        #pragma unroll
        for (int j = 0; j < 8; j++)
            w1F[(size_t)c * 8 + j] = f2bf(w1[(size_t)(kb + j) * CM_ + n]);
    }
}

// Redundant per-block BN finish (bit-identical in every block).
static __device__ __forceinline__ void bn_finish_lds(
    const float* __restrict__ slots, const float* __restrict__ g,
    const float* __restrict__ be, float* bnpL, int t)
{
    if (t < CM_) {
        float s = 0.f, q2 = 0.f;
        #pragma unroll
        for (int sl = 0; sl < NSLOT; sl++) {
            s  += slots[sl * 256 + t];
            q2 += slots[sl * 256 + CM_ + t];
        }
        const float invn = 1.0f / (float)NTOT;
        float mu = s * invn, var = q2 * invn - mu * mu;
        float sc = g[t] * rsqrtf(var + BN_EPS_);
        bnpL[t] = sc;
        bnpL[CM_ + t] = be[t] - mu * sc;
    }
}

// ---------------------------------------------------------------------------
// K1: 64 points/block, 2048 blocks. KNN sq-pass spread over ALL 256 threads
// (4 threads/point x 7 slots each -> sqL in LDS, overlaid on xstage storage;
// r11 counters: 1-wave KNN left 3 waves barrier-idle, fused1 73us vs ~51us
// byte-floor). Serial first-3 select (reference scan order) then reads sqL
// from LDS -- no memory latency on the select. y0 stored uint4.
// ---------------------------------------------------------------------------
__global__ __launch_bounds__(256, 2) void fused1_kernel(
    const float* __restrict__ xyz1, const float* __restrict__ xyz2,
    const float* __restrict__ feat1, const float* __restrict__ feat2,
    const unsigned short* __restrict__ w0F, const float* __restrict__ b0,
    uint4* __restrict__ y0w4, float* __restrict__ slots0)
{
    // overlay: phase A = sqL[64][28] f32 (7168 B); phase B = xstage[64][XP] u16
    __shared__ __align__(16) char smem[64 * XP * 2];   // 16896 B
    __shared__ int   selL[64][NS_];
    __shared__ float wgtL[64][NS_];
    __shared__ float wsum[4][CM_], wsq[4][CM_];

    float (*sqL)[28] = (float (*)[28])smem;
    unsigned short (*xstage)[XP] = (unsigned short (*)[XP])smem;

    const int t = threadIdx.x;
    const int blk = blockIdx.x;
    const int pbase = blk * 64;
    const int bidx = blk >> 10;
    const int wv = t >> 6, lane = t & 63;
    const int m = lane & 15, q = lane >> 4;
    const int lr = wv * 16 + m;
    const int row0 = pbase + lr;

    // feat1 -> A-frags kk=0,1 (loads issue first, overlap KNN latency)
    short8 af[2];
    #pragma unroll
    for (int kk = 0; kk < 2; kk++) {
        const float* sp = feat1 + (size_t)row0 * C1_ + kk * 32 + q * 8;
        float4 fa = *(const float4*)(sp), fb = *(const float4*)(sp + 4);
        short8 a;
        a[0] = f2bf(fa.x); a[1] = f2bf(fa.y); a[2] = f2bf(fa.z); a[3] = f2bf(fa.w);
        a[4] = f2bf(fb.x); a[5] = f2bf(fb.y); a[6] = f2bf(fb.z); a[7] = f2bf(fb.w);
        af[kk] = a;
    }

    // KNN sq-pass: all 256 threads; point p = t>>2, slot group g = t&3
    {
        const int p = t >> 2, g = t & 3;
        const int pt = pbase + p;
        const int n = pt & (NPT - 1);
        const int h = n >> 10, w = n & (W_ - 1);
        const float* p1 = xyz1 + (size_t)pt * 3;
        float x1 = p1[0], y1 = p1[1], z1 = p1[2];
        const float* x2b = xyz2 + (size_t)bidx * NPT * 3;
        #pragma unroll
        for (int j = 0; j < 7; j++) {
            int k = g * 7 + j;
            if (k < 25) {
                int dh = k / 5 - 2, dw = k % 5 - 2;
                int nh = h + dh, nw = w + dw;
                bool inb = (nh >= 0) && (nh < H_) && (nw >= 0) && (nw < W_);
                int ch = min(max(nh, 0), H_ - 1);
                int cw = min(max(nw, 0), W_ - 1);
                const float* p2 = x2b + (size_t)(ch * W_ + cw) * 3;
                float dx = p2[0] - x1, dy = p2[1] - y1, dz = p2[2] - z1;
                sqL[p][k] = inb ? (dx * dx + dy * dy + dz * dz) : 3.4e38f;
            }
        }
    }
    __syncthreads();

    // serial first-3 select (reference row-major scan order), sq from LDS
    if (t < 64) {
        const int pt = pbase + t;
        const int n = pt & (NPT - 1);
        const int h = n >> 10, w = n & (W_ - 1);
        const float* p1 = xyz1 + (size_t)pt * 3;
        float x1 = p1[0], y1 = p1[1], z1 = p1[2];

        int   s0 = 0, s1 = 0, s2 = 0;
        float d0 = 0.f, d1 = 0.f, d2 = 0.f;
        int cnt = 0;
        #pragma unroll
        for (int k = 0; k < 25; k++) {
            const int dh = k / 5 - 2, dw = k % 5 - 2;
            int ch = min(max(h + dh, 0), H_ - 1);
            int cw = min(max(w + dw, 0), W_ - 1);
            int nidx = ch * W_ + cw;
            float sk = sqL[t][k];
            if (sk < DIST2_ && cnt < NS_) {
                if (cnt == 0)      { s0 = nidx; d0 = sk; }
                else if (cnt == 1) { s1 = nidx; d1 = sk; }
                else               { s2 = nidx; d2 = sk; }
                cnt++;
            }
        }
        float self2 = x1 * x1 + y1 * y1 + z1 * z1;
        float dd0 = (cnt > 0) ? d0 : self2;
        float dd1 = (cnt > 1) ? d1 : self2;
        float dd2 = (cnt > 2) ? d2 : self2;
        dd0 = fmaxf(dd0, 1e-10f); dd1 = fmaxf(dd1, 1e-10f); dd2 = fmaxf(dd2, 1e-10f);
        float i0 = 1.0f / dd0, i1 = 1.0f / dd1, i2 = 1.0f / dd2;
        float norm = i0 + i1 + i2;
        selL[t][0] = (cnt > 0) ? s0 : 0;
        selL[t][1] = (cnt > 1) ? s1 : 0;
        selL[t][2] = (cnt > 2) ? s2 : 0;
        wgtL[t][0] = (cnt > 0) ? i0 / norm : 0.f;
        wgtL[t][1] = (cnt > 1) ? i1 / norm : 0.f;
        wgtL[t][2] = (cnt > 2) ? i2 / norm : 0.f;
    }
    __syncthreads();   // select done; smem may now be reused as xstage

    // IDW interp -> xstage (overwrites sqL region -- safe after barrier)
    const float* f2b = feat2 + (size_t)bidx * NPT * C2_;
    #pragma unroll
    for (int i = 0; i < 8; i++) {
        int idx = t + i * 256;
        int p = idx >> 5, c4 = (idx & 31) << 2;
        float ax = 0.f, ay = 0.f, az = 0.f, aw = 0.f;
        #pragma unroll
        for (int j = 0; j < NS_; j++) {
            float wj = wgtL[p][j];
            const float4 f = *(const float4*)(f2b + (size_t)selL[p][j] * C2_ + c4);
            ax += wj * f.x; ay += wj * f.y; az += wj * f.z; aw += wj * f.w;
        }
        ushort4 u;
        u.x = f2bf(ax); u.y = f2bf(ay); u.z = f2bf(az); u.w = f2bf(aw);
        *(ushort4*)&xstage[p][c4] = u;
    }
    __syncthreads();

    floatx4 acc[8];
    #pragma unroll
    for (int nt = 0; nt < 8; nt++) acc[nt] = (floatx4){0.f, 0.f, 0.f, 0.f};

    #pragma unroll
    for (int kk = 0; kk < 6; kk++) {
        short8 bw[8];
        #pragma unroll
        for (int nt = 0; nt < 8; nt++)
            bw[nt] = *(const short8*)(w0F + ((size_t)(kk * 8 + nt) * 64 + lane) * 8);
        short8 a = (kk < 2) ? af[kk]
                            : *(const short8*)&xstage[lr][(kk - 2) * 32 + q * 8];
        #pragma unroll
        for (int nt = 0; nt < 8; nt++)
            acc[nt] = __builtin_amdgcn_mfma_f32_16x16x32_bf16(a, bw[nt], acc[nt], 0, 0, 0);
    }

    // epilogue: y0 uint4 frag-pair stores + BN0 stats
    #pragma unroll
    for (int nt2 = 0; nt2 < 4; nt2++) {
        const int ntA = 2 * nt2, ntB = ntA + 1;
        const int nA = ntA * 16 + m, nB = ntB * 16 + m;
        float bvA = b0[nA], bvB = b0[nB];
        unsigned u0 = packbf(acc[ntA][0] + bvA, acc[ntA][1] + bvA);
        unsigned u1 = packbf(acc[ntA][2] + bvA, acc[ntA][3] + bvA);
        unsigned u2 = packbf(acc[ntB][0] + bvB, acc[ntB][1] + bvB);
        unsigned u3 = packbf(acc[ntB][2] + bvB, acc[ntB][3] + bvB);
        y0w4[((size_t)(blk * 4 + wv) * 4 + nt2) * 64 + lane] = make_uint4(u0, u1, u2, u3);
        float a0 = bflo(u0), a1 = bfhi(u0), a2 = bflo(u1), a3 = bfhi(u1);
        float b0v = bflo(u2), b1v = bfhi(u2), b2v = bflo(u3), b3v = bfhi(u3);
        float sA = a0 + a1 + a2 + a3, qA = a0*a0 + a1*a1 + a2*a2 + a3*a3;
        float sB = b0v + b1v + b2v + b3v, qB = b0v*b0v + b1v*b1v + b2v*b2v + b3v*b3v;
        sA += __shfl_xor(sA, 16, 64); qA += __shfl_xor(qA, 16, 64);
        sA += __shfl_xor(sA, 32, 64); qA += __shfl_xor(qA, 32, 64);
        sB += __shfl_xor(sB, 16, 64); qB += __shfl_xor(qB, 16, 64);
        sB += __shfl_xor(sB, 32, 64); qB += __shfl_xor(qB, 32, 64);
        if (q == 0) {
            wsum[wv][nA] = sA; wsq[wv][nA] = qA;
            wsum[wv][nB] = sB; wsq[wv][nB] = qB;
        }
    }
    __syncthreads();

    float* slot = slots0 + (size_t)(blk & (NSLOT - 1)) * 256;
    if (t < CM_)
        atomicAdd(&slot[t], wsum[0][t] + wsum[1][t] + wsum[2][t] + wsum[3][t]);
    else
        atomicAdd(&slot[t], wsq[0][t - CM_] + wsq[1][t - CM_] + wsq[2][t - CM_] + wsq[3][t - CM_]);
}

// ---------------------------------------------------------------------------
// K2: uint4 in (y0), uint4 out (y1); BN0 finished in-block; kk=0 B-frags
// prefetched before the BN/LDS phase (independent of it).
// ---------------------------------------------------------------------------
__global__ __launch_bounds__(256, 2) void fused2_kernel(
    const uint4* __restrict__ y0w4, const float* __restrict__ slots0,
    const float* __restrict__ g0, const float* __restrict__ be0,
    const unsigned short* __restrict__ w1F, const float* __restrict__ b1,
    uint4* __restrict__ y1w4, float* __restrict__ slots1)
{
    __shared__ unsigned short x1s[64][XP];
    __shared__ float wsum[4][CM_], wsq[4][CM_];
    __shared__ float bnpL[2 * CM_];

    const int t = threadIdx.x;
    const int blk = blockIdx.x;
    const int wv = t >> 6, lane = t & 63;
    const int m = lane & 15, q = lane >> 4;
    const int lr = wv * 16 + m;

    // kk=0 B-frag prefetch (independent of BN/LDS phase below)
    short8 bw0[8];
    #pragma unroll
    for (int nt = 0; nt < 8; nt++)
        bw0[nt] = *(const short8*)(w1F + ((size_t)nt * 64 + lane) * 8);

    bn_finish_lds(slots0, g0, be0, bnpL, t);
    __syncthreads();

    #pragma unroll
    for (int nt2 = 0; nt2 < 4; nt2++) {
        const int nA = (2 * nt2) * 16 + m, nB = nA + 16;
        float scA = bnpL[nA], shA = bnpL[CM_ + nA];
        float scB = bnpL[nB], shB = bnpL[CM_ + nB];
        uint4 u = y0w4[((size_t)(blk * 4 + wv) * 4 + nt2) * 64 + lane];
        int rb = wv * 16 + q * 4;
        x1s[rb + 0][nA] = f2bf(fmaxf(bflo(u.x) * scA + shA, 0.f));
        x1s[rb + 1][nA] = f2bf(fmaxf(bfhi(u.x) * scA + shA, 0.f));
        x1s[rb + 2][nA] = f2bf(fmaxf(bflo(u.y) * scA + shA, 0.f));
        x1s[rb + 3][nA] = f2bf(fmaxf(bfhi(u.y) * scA + shA, 0.f));
        x1s[rb + 0][nB] = f2bf(fmaxf(bflo(u.z) * scB + shB, 0.f));
        x1s[rb + 1][nB] = f2bf(fmaxf(bfhi(u.z) * scB + shB, 0.f));
        x1s[rb + 2][nB] = f2bf(fmaxf(bflo(u.w) * scB + shB, 0.f));
        x1s[rb + 3][nB] = f2bf(fmaxf(bfhi(u.w) * scB + shB, 0.f));
    }
    __syncthreads();

    floatx4 acc[8];
    #pragma unroll
    for (int nt = 0; nt < 8; nt++) acc[nt] = (floatx4){0.f, 0.f, 0.f, 0.f};

    #pragma unroll
    for (int kk = 0; kk < 4; kk++) {
        short8 bw[8];
        #pragma unroll
        for (int nt = 0; nt < 8; nt++)
            bw[nt] = (kk == 0) ? bw0[nt]
                   : *(const short8*)(w1F + ((size_t)(kk * 8 + nt) * 64 + lane) * 8);
        short8 a = *(const short8*)&x1s[lr][kk * 32 + q * 8];
        #pragma unroll
        for (int nt = 0; nt < 8; nt++)
            acc[nt] = __builtin_amdgcn_mfma_f32_16x16x32_bf16(a, bw[nt], acc[nt], 0, 0, 0);
    }

    #pragma unroll
    for (int nt2 = 0; nt2 < 4; nt2++) {
        const int ntA = 2 * nt2, ntB = ntA + 1;
        const int nA = ntA * 16 + m, nB = ntB * 16 + m;
        float bvA = b1[nA], bvB = b1[nB];
        unsigned u0 = packbf(acc[ntA][0] + bvA, acc[ntA][1] + bvA);
        unsigned u1 = packbf(acc[ntA][2] + bvA, acc[ntA][3] + bvA);
        unsigned u2 = packbf(acc[ntB][0] + bvB, acc[ntB][1] + bvB);
        unsigned u3 = packbf(acc[ntB][2] + bvB, acc[ntB][3] + bvB);
        y1w4[((size_t)(blk * 4 + wv) * 4 + nt2) * 64 + lane] = make_uint4(u0, u1, u2, u3);
        float a0 = bflo(u0), a1 = bfhi(u0), a2 = bflo(u1), a3 = bfhi(u1);
        float c0 = bflo(u2), c1 = bfhi(u2), c2 = bflo(u3), c3 = bfhi(u3);
        float sA = a0 + a1 + a2 + a3, qA = a0*a0 + a1*a1 + a2*a2 + a3*a3;
        float sB = c0 + c1 + c2 + c3, qB = c0*c0 + c1*c1 + c2*c2 + c3*c3;
        sA += __shfl_xor(sA, 16, 64); qA += __shfl_xor(qA, 16, 64);
        sA += __shfl_xor(sA, 32, 64); qA += __shfl_xor(qA, 32, 64);
        sB += __shfl_xor(sB, 16, 64); qB += __shfl_xor(qB, 16, 64);
        sB += __shfl_xor(sB, 32, 64); qB += __shfl_xor(qB, 32, 64);
        if (q == 0) {
            wsum[wv][nA] = sA; wsq[wv][nA] = qA;
            wsum[wv][nB] = sB; wsq[wv][nB] = qB;
        }
    }
    __syncthreads();

    float* slot = slots1 + (size_t)(blk & (NSLOT - 1)) * 256;
    if (t < CM_)
        atomicAdd(&slot[t], wsum[0][t] + wsum[1][t] + wsum[2][t] + wsum[3][t]);
    else
        atomicAdd(&slot[t], wsq[0][t - CM_] + wsq[1][t - CM_] + wsq[2][t - CM_] + wsq[3][t - CM_]);
}

// ---------------------------------------------------------------------------
// K3: uint4 in (y1); BN1 finished in-block; LDS transpose -> f32 out.
// ---------------------------------------------------------------------------
__global__ __launch_bounds__(256) void bn_out_kernel(
    const uint4* __restrict__ y1w4, const float* __restrict__ slots1,
    const float* __restrict__ g1, const float* __restrict__ be1,
    float* __restrict__ out)
{
    __shared__ float xo[64][XP];
    __shared__ float bnpL[2 * CM_];
    const int t = threadIdx.x;
    const int blk = blockIdx.x;
    const int wv = t >> 6, lane = t & 63;
    const int m = lane & 15, q = lane >> 4;

    bn_finish_lds(slots1, g1, be1, bnpL, t);
    __syncthreads();

    #pragma unroll
    for (int nt2 = 0; nt2 < 4; nt2++) {
        const int nA = (2 * nt2) * 16 + m, nB = nA + 16;
        float scA = bnpL[nA], shA = bnpL[CM_ + nA];
        float scB = bnpL[nB], shB = bnpL[CM_ + nB];
        uint4 u = y1w4[((size_t)(blk * 4 + wv) * 4 + nt2) * 64 + lane];
        int rb = wv * 16 + q * 4;
        xo[rb + 0][nA] = fmaxf(bflo(u.x) * scA + shA, 0.f);
        xo[rb + 1][nA] = fmaxf(bfhi(u.x) * scA + shA, 0.f);
        xo[rb + 2][nA] = fmaxf(bflo(u.y) * scA + shA, 0.f);
        xo[rb + 3][nA] = fmaxf(bfhi(u.y) * scA + shA, 0.f);
        xo[rb + 0][nB] = fmaxf(bflo(u.z) * scB + shB, 0.f);
        xo[rb + 1][nB] = fmaxf(bfhi(u.z) * scB + shB, 0.f);
        xo[rb + 2][nB] = fmaxf(bflo(u.w) * scB + shB, 0.f);
        xo[rb + 3][nB] = fmaxf(bfhi(u.w) * scB + shB, 0.f);
    }
    __syncthreads();

    const int pbase = blk * 64;
    #pragma unroll
    for (int i = 0; i < 8; i++) {
        int idx = t + i * 256;
        int p = idx >> 5, c4 = (idx & 31) << 2;
        float4 v = *(const float4*)&xo[p][c4];
        *(float4*)(out + (size_t)(pbase + p) * CM_ + c4) = v;
    }
}

// ---------------------------------------------------------------------------
extern "C" void kernel_launch(void* const* d_in, const int* in_sizes, int n_in,
                              void* d_out, int out_size, void* d_ws, size_t ws_size,
                              hipStream_t stream)
{
    const float* xyz1  = (const float*)d_in[0];
    const float* xyz2  = (const float*)d_in[1];
    const float* feat1 = (const float*)d_in[2];
    const float* feat2 = (const float*)d_in[3];
    const float* w0    = (const float*)d_in[4];
    const float* b0    = (const float*)d_in[5];
    const float* g0    = (const float*)d_in[6];
    const float* be0   = (const float*)d_in[7];
    const float* w1    = (const float*)d_in[8];
    const float* b1    = (const float*)d_in[9];
    const float* g1    = (const float*)d_in[10];
    const float* be1   = (const float*)d_in[11];
    float* out = (float*)d_out;

    char* ws = (char*)d_ws;
    // ws: slots0 32K | slots1 32K | w0F 48K | w1F 32K | y0w 33.5M | y1w 33.5M
    float* slots0       = (float*)(ws);
    float* slots1       = (float*)(ws + (size_t)NSLOT * 256 * 4);
    char*  p            = ws + 2 * (size_t)NSLOT * 256 * 4;
    unsigned short* w0F = (unsigned short*)p;  p += (size_t)CIN_ * CM_ * 2;
    unsigned short* w1F = (unsigned short*)p;  p += (size_t)CM_ * CM_ * 2;
    uint4* y0w4         = (uint4*)p;           p += (size_t)NTOT * CM_ * 2;
    uint4* y1w4         = (uint4*)p;

    hipMemsetAsync(ws, 0, 2 * (size_t)NSLOT * 256 * 4, stream);  // zero stat slots

    prep_w_kernel<<<20, 256, 0, stream>>>(w0, w1, w0F, w1F);
    fused1_kernel<<<NTOT / 64, 256, 0, stream>>>(xyz1, xyz2, feat1, feat2,
                                                 w0F, b0, y0w4, slots0);
    fused2_kernel<<<NTOT / 64, 256, 0, stream>>>(y0w4, slots0, g0, be0,
                                                 w1F, b1, y1w4, slots1);
    bn_out_kernel<<<NTOT / 64, 256, 0, stream>>>(y1w4, slots1, g1, be1, out);
}